// Round 1
// baseline (3895.196 us; speedup 1.0000x reference)
//
#include <hip/hip_runtime.h>
#include <math.h>

#define T_SEQ   1024
#define BATCH   2
#define CDIM    1024
#define NHEAD   16
#define VHEAD   32
#define NOPE_D  32
#define ROPED   64
#define KEEP    256
#define HEAD_D  96   // NOPE + ROPE
#define SCALE_ATTN 0.1020620726159658f  // 1/sqrt(96)

// ---------------------------------------------------------------------------
// Generic fp32 tiled GEMM: C[M,N] = A[M,K] @ B[K,N], row-major.
// 64x64 tile, 256 threads, 4x4 per thread, K-step 16.
// ---------------------------------------------------------------------------
__global__ __launch_bounds__(256) void gemm_tiled(const float* __restrict__ A,
                                                  const float* __restrict__ B,
                                                  float* __restrict__ C,
                                                  int M, int N, int K) {
    __shared__ float As[16][65];
    __shared__ float Bs[16][64];
    int tid = threadIdx.x;
    int tx = tid & 15, ty = tid >> 4;
    int row0 = blockIdx.y * 64, col0 = blockIdx.x * 64;
    float acc[4][4] = {};
    for (int k0 = 0; k0 < K; k0 += 16) {
#pragma unroll
        for (int r = 0; r < 4; r++) {
            int idx = tid + 256 * r;
            int kk = idx & 15, m = idx >> 4;
            int gr = row0 + m, gc = k0 + kk;
            As[kk][m] = (gr < M && gc < K) ? A[(size_t)gr * K + gc] : 0.f;
        }
#pragma unroll
        for (int r = 0; r < 4; r++) {
            int idx = tid + 256 * r;
            int n = idx & 63, kk = idx >> 6;
            int gr = k0 + kk, gc = col0 + n;
            Bs[kk][n] = (gr < K && gc < N) ? B[(size_t)gr * N + gc] : 0.f;
        }
        __syncthreads();
#pragma unroll
        for (int kk = 0; kk < 16; kk++) {
            float a[4], b[4];
#pragma unroll
            for (int i = 0; i < 4; i++) a[i] = As[kk][ty + 16 * i];
#pragma unroll
            for (int j = 0; j < 4; j++) b[j] = Bs[kk][tx + 16 * j];
#pragma unroll
            for (int i = 0; i < 4; i++)
#pragma unroll
                for (int j = 0; j < 4; j++) acc[i][j] += a[i] * b[j];
        }
        __syncthreads();
    }
#pragma unroll
    for (int i = 0; i < 4; i++) {
        int gr = row0 + ty + 16 * i;
        if (gr >= M) continue;
#pragma unroll
        for (int j = 0; j < 4; j++) {
            int gc = col0 + tx + 16 * j;
            if (gc < N) C[(size_t)gr * N + gc] = acc[i][j];
        }
    }
}

// ---------------------------------------------------------------------------
// RMSNorm over last dim, in place. One wave per row.
// ---------------------------------------------------------------------------
__global__ void rms_rows(float* __restrict__ buf, const float* __restrict__ g, int D) {
    int row = blockIdx.x;
    int lane = threadIdx.x;  // blockDim = 64
    float ss = 0.f;
    for (int d = lane; d < D; d += 64) {
        float v = buf[(size_t)row * D + d];
        ss += v * v;
    }
    for (int off = 32; off; off >>= 1) ss += __shfl_xor(ss, off, 64);
    float r = rsqrtf(ss / (float)D + 1e-6f);
    for (int d = lane; d < D; d += 64) buf[(size_t)row * D + d] *= r * g[d];
}

// ---------------------------------------------------------------------------
// RoPE in place. Pairs (i, i+32), i in [0,32). pos = row % posmod.
// ---------------------------------------------------------------------------
__global__ void rope_inplace(float* __restrict__ buf, int nrows, int rstride,
                             int nheads, int hstride, int roff, int posmod,
                             float scale) {
    int total = nrows * nheads * 32;
    for (int it = blockIdx.x * blockDim.x + threadIdx.x; it < total;
         it += gridDim.x * blockDim.x) {
        int i = it & 31;
        int hr = it >> 5;
        int h = hr % nheads;
        int row = hr / nheads;
        int pos = row % posmod;
        float expo = (float)i * (1.0f / 32.0f);
        float f = 1.0f / powf(10000.0f, expo);
        float a = (float)pos * f;
        float s, c;
        sincosf(a, &s, &c);
        size_t base = (size_t)row * rstride + (size_t)h * hstride + roff;
        float v1 = buf[base + i], v2 = buf[base + 32 + i];
        buf[base + i]      = (v1 * c - v2 * s) * scale;
        buf[base + 32 + i] = (v1 * s + v2 * c) * scale;
    }
}

// ---------------------------------------------------------------------------
// scores = x @ w_imp ; gate partial sums (pre-mean) via atomics.
// One wave per (b,t) row.
// ---------------------------------------------------------------------------
__global__ void scores_gate(const float* __restrict__ x,
                            const float* __restrict__ w_imp,
                            const float* __restrict__ w_gate,
                            float* __restrict__ scores,
                            float* __restrict__ gate_raw) {
    int wid = (blockIdx.x * blockDim.x + threadIdx.x) >> 6;
    int lane = threadIdx.x & 63;
    if (wid >= BATCH * T_SEQ) return;
    int b = wid >> 10;
    const float* xr = x + (size_t)wid * CDIM;
    float s0 = 0, g0 = 0, g1 = 0, g2 = 0;
    for (int c = lane; c < CDIM; c += 64) {
        float xv = xr[c];
        s0 += xv * w_imp[c];
        g0 += xv * w_gate[c * 3 + 0];
        g1 += xv * w_gate[c * 3 + 1];
        g2 += xv * w_gate[c * 3 + 2];
    }
    for (int off = 32; off; off >>= 1) {
        s0 += __shfl_xor(s0, off, 64);
        g0 += __shfl_xor(g0, off, 64);
        g1 += __shfl_xor(g1, off, 64);
        g2 += __shfl_xor(g2, off, 64);
    }
    if (lane == 0) {
        scores[wid] = s0;
        atomicAdd(&gate_raw[b * 3 + 0], g0);
        atomicAdd(&gate_raw[b * 3 + 1], g1);
        atomicAdd(&gate_raw[b * 3 + 2], g2);
    }
}

__global__ void gate_final(const float* __restrict__ gate_raw, float* __restrict__ gate) {
    int b = threadIdx.x;
    if (b >= BATCH) return;
    float v0 = gate_raw[b * 3 + 0] / (float)T_SEQ;
    float v1 = gate_raw[b * 3 + 1] / (float)T_SEQ;
    float v2 = gate_raw[b * 3 + 2] / (float)T_SEQ;
    float m = fmaxf(v0, fmaxf(v1, v2));
    float e0 = expf(v0 - m), e1 = expf(v1 - m), e2 = expf(v2 - m);
    float s = e0 + e1 + e2;
    gate[b * 3 + 0] = e0 / s;
    gate[b * 3 + 1] = e1 / s;
    gate[b * 3 + 2] = e2 / s;
}

// ---------------------------------------------------------------------------
// Top-k (KEEP=256 of 1024) per batch via rank counting, sorted ascending idx.
// Rank = #{j : s_j > s_i || (s_j == s_i && j < i)}  (matches lax.top_k ties).
// One block of 1024 threads per batch.
// ---------------------------------------------------------------------------
__global__ void topk_kernel(const float* __restrict__ scores, int* __restrict__ idx) {
    int b = blockIdx.x;
    __shared__ float s[1024];
    __shared__ int ps[1024];
    int t = threadIdx.x;
    s[t] = scores[b * T_SEQ + t];
    __syncthreads();
    float mine = s[t];
    int rank = 0;
    for (int j = 0; j < 1024; j++) {
        float v = s[j];
        rank += (v > mine) || (v == mine && j < t);
    }
    int selv = (rank < KEEP) ? 1 : 0;
    ps[t] = selv;
    __syncthreads();
    for (int off = 1; off < 1024; off <<= 1) {
        int add = (t >= off) ? ps[t - off] : 0;
        __syncthreads();
        ps[t] += add;
        __syncthreads();
    }
    if (selv) idx[b * KEEP + ps[t] - 1] = t;
}

__global__ void gather_sel(const float* __restrict__ x, const int* __restrict__ idx,
                           float* __restrict__ sel) {
    for (size_t i = (size_t)blockIdx.x * blockDim.x + threadIdx.x;
         i < (size_t)BATCH * KEEP * CDIM; i += (size_t)gridDim.x * blockDim.x) {
        int c = (int)(i & (CDIM - 1));
        int r = (int)((i >> 10) & (KEEP - 1));
        int b = (int)(i >> 18);
        sel[i] = x[((size_t)b * T_SEQ + idx[b * KEEP + r]) * CDIM + c];
    }
}

// ---------------------------------------------------------------------------
// Fused 3-branch flash attention + gate combine.
// Grid: (T/4, NHEAD, BATCH). Block: 256 = 4 waves, one query row per wave.
// K tiles of 64 keys staged in LDS (pad 97 -> conflict-free dot reads).
// phase 0: k=[kn|krope], v=v1, causal. phase 1: ks/vs, 256 keys, full.
// phase 2: kw/vw, causal.
// ---------------------------------------------------------------------------
__global__ __launch_bounds__(256) void flash_fused(
    const float* __restrict__ qn, const float* __restrict__ qr,
    const float* __restrict__ kn, const float* __restrict__ kr,
    const float* __restrict__ v1, const float* __restrict__ ksr,
    const float* __restrict__ vsr, const float* __restrict__ kwr,
    const float* __restrict__ vwr, const float* __restrict__ gate,
    float* __restrict__ out) {
    __shared__ float Kt[64 * 97];
    __shared__ float Vt[64 * 32];
    int b = blockIdx.z, h = blockIdx.y;
    int w = threadIdx.x >> 6, lane = threadIdx.x & 63;
    int t = blockIdx.x * 4 + w;
    int tmaxb = blockIdx.x * 4 + 3;
    int laneL = lane & 31;
    size_t rq = (size_t)b * T_SEQ + t;

    float qv[HEAD_D];
#pragma unroll
    for (int d = 0; d < NOPE_D; d++) qv[d] = qn[rq * 512 + h * 32 + d];
#pragma unroll
    for (int d = 0; d < ROPED; d++) qv[NOPE_D + d] = qr[rq * 1024 + h * 64 + d];

    float comb = 0.f;
    for (int phase = 0; phase < 3; phase++) {
        int nk = (phase == 1) ? KEEP : T_SEQ;
        bool causal = (phase != 1);
        float m = -1e30f, l = 0.f, acc = 0.f;
        int ntiles = causal ? (tmaxb / 64 + 1) : (nk / 64);
        for (int kt = 0; kt < ntiles; kt++) {
            int j0 = kt * 64;
            __syncthreads();
            for (int idx = threadIdx.x; idx < 64 * 96; idx += 256) {
                int jj = idx / 96, d = idx % 96;
                int j = j0 + jj;
                float v = 0.f;
                if (j < nk) {
                    if (phase == 0)
                        v = (d < 32) ? kn[((size_t)b * T_SEQ + j) * 512 + h * 32 + d]
                                     : kr[((size_t)b * T_SEQ + j) * 64 + (d - 32)];
                    else if (phase == 1)
                        v = ksr[((size_t)b * KEEP + j) * 1536 + h * 96 + d];
                    else
                        v = kwr[((size_t)b * T_SEQ + j) * 1536 + h * 96 + d];
                }
                Kt[jj * 97 + d] = v;
            }
            for (int idx = threadIdx.x; idx < 64 * 32; idx += 256) {
                int jj = idx >> 5, d = idx & 31;
                int j = j0 + jj;
                float v = 0.f;
                if (j < nk) {
                    if (phase == 0)
                        v = v1[((size_t)b * T_SEQ + j) * 512 + h * 32 + d];
                    else if (phase == 1)
                        v = vsr[((size_t)b * KEEP + j) * 512 + h * 32 + d];
                    else
                        v = vwr[((size_t)b * T_SEQ + j) * 512 + h * 32 + d];
                }
                Vt[jj * 32 + d] = v;
            }
            __syncthreads();

            int j = j0 + lane;
            float s = -1e30f;
            bool valid = (j < nk) && (!causal || j <= t);
            if (valid) {
                float dot = 0.f;
                const float* kp = &Kt[lane * 97];
#pragma unroll
                for (int d = 0; d < HEAD_D; d++) dot += qv[d] * kp[d];
                s = dot * SCALE_ATTN;
            }
            float mt = s;
            for (int off = 32; off; off >>= 1) mt = fmaxf(mt, __shfl_xor(mt, off, 64));
            float mnew = fmaxf(m, mt);
            float alpha = expf(m - mnew);
            float p = expf(s - mnew);
            float ps = p;
            for (int off = 32; off; off >>= 1) ps += __shfl_xor(ps, off, 64);
            l = l * alpha + ps;
            acc *= alpha;
#pragma unroll 8
            for (int jj2 = 0; jj2 < 64; jj2++) {
                float pj = __shfl(p, jj2, 64);
                acc += pj * Vt[jj2 * 32 + laneL];
            }
            m = mnew;
        }
        float g = gate[b * 3 + phase];
        comb += g * (acc / l);
    }
    if (lane < 32) out[rq * 512 + h * 32 + lane] = comb;
}

// ---------------------------------------------------------------------------
extern "C" void kernel_launch(void* const* d_in, const int* in_sizes, int n_in,
                              void* d_out, int out_size, void* d_ws, size_t ws_size,
                              hipStream_t stream) {
    const float* x        = (const float*)d_in[0];
    const float* w_cq     = (const float*)d_in[1];
    const float* g_qnorm  = (const float*)d_in[2];
    const float* w_dqn    = (const float*)d_in[3];
    const float* w_dqr    = (const float*)d_in[4];
    const float* w_ckv    = (const float*)d_in[5];
    const float* g_kvnorm = (const float*)d_in[6];
    const float* w_dkn    = (const float*)d_in[7];
    const float* w_dv     = (const float*)d_in[8];
    const float* w_krope  = (const float*)d_in[9];
    const float* w_imp    = (const float*)d_in[10];
    const float* w_selk   = (const float*)d_in[11];
    const float* w_selv   = (const float*)d_in[12];
    const float* w_wink   = (const float*)d_in[13];
    const float* w_winv   = (const float*)d_in[14];
    const float* w_gate   = (const float*)d_in[15];
    const float* w_proj   = (const float*)d_in[16];
    float* out = (float*)d_out;

    const int BT = BATCH * T_SEQ;  // 2048
    const int BS = BATCH * KEEP;   // 512

    float* ws = (float*)d_ws;
    size_t o = 0;
    float* nq     = ws + o; o += (size_t)BT * 96;
    float* ckv    = ws + o; o += (size_t)BT * 32;
    float* qn     = ws + o; o += (size_t)BT * 512;
    float* qr     = ws + o; o += (size_t)BT * 1024;
    float* knb    = ws + o; o += (size_t)BT * 512;
    float* vvb    = ws + o; o += (size_t)BT * 512;
    float* kro    = ws + o; o += (size_t)BT * 64;
    float* kwb    = ws + o; o += (size_t)BT * 1536;
    float* vwb    = ws + o; o += (size_t)BT * 512;
    float* ksb    = ws + o; o += (size_t)BS * 1536;
    float* vsb    = ws + o; o += (size_t)BS * 512;
    float* selb   = ws + o; o += (size_t)BS * CDIM;
    float* scores = ws + o; o += 2048;
    float* gateraw= ws + o; o += 8;
    float* gatef  = ws + o; o += 8;
    int*   idx    = (int*)(ws + o); o += 512;
    float* attn   = ws + o; o += (size_t)BT * 512;

    hipMemsetAsync(gateraw, 0, 8 * sizeof(float), stream);

    dim3 blk(256);
    auto gemm = [&](const float* A, const float* Bm, float* C, int M, int N, int K) {
        dim3 grid((N + 63) / 64, (M + 63) / 64);
        gemm_tiled<<<grid, blk, 0, stream>>>(A, Bm, C, M, N, K);
    };

    // Projections off x
    gemm(x, w_cq, nq, BT, 96, CDIM);
    rms_rows<<<BT, 64, 0, stream>>>(nq, g_qnorm, 96);
    gemm(nq, w_dqn, qn, BT, 512, 96);
    gemm(nq, w_dqr, qr, BT, 1024, 96);
    rope_inplace<<<2048, 256, 0, stream>>>(qr, BT, 1024, 16, 64, 0, T_SEQ, 1.0f);

    gemm(x, w_ckv, ckv, BT, 32, CDIM);
    rms_rows<<<BT, 64, 0, stream>>>(ckv, g_kvnorm, 32);
    gemm(ckv, w_dkn, knb, BT, 512, 32);
    gemm(ckv, w_dv, vvb, BT, 512, 32);

    gemm(x, w_krope, kro, BT, 64, CDIM);
    rope_inplace<<<256, 256, 0, stream>>>(kro, BT, 64, 1, 0, 0, T_SEQ, 1.0f / NHEAD);

    gemm(x, w_wink, kwb, BT, 1536, CDIM);
    rope_inplace<<<2048, 256, 0, stream>>>(kwb, BT, 1536, 16, 96, 32, T_SEQ, 1.0f);
    gemm(x, w_winv, vwb, BT, 512, CDIM);

    // scores + gate
    scores_gate<<<(BT * 64 + 255) / 256, 256, 0, stream>>>(x, w_imp, w_gate, scores, gateraw);
    gate_final<<<1, 64, 0, stream>>>(gateraw, gatef);

    // top-k select
    topk_kernel<<<BATCH, 1024, 0, stream>>>(scores, idx);
    gather_sel<<<2048, 256, 0, stream>>>(x, idx, selb);
    gemm(selb, w_selk, ksb, BS, 1536, CDIM);
    rope_inplace<<<512, 256, 0, stream>>>(ksb, BS, 1536, 16, 96, 32, KEEP, 1.0f);
    gemm(selb, w_selv, vsb, BS, 512, CDIM);

    // fused attention
    dim3 fgrid(T_SEQ / 4, NHEAD, BATCH);
    flash_fused<<<fgrid, 256, 0, stream>>>(qn, qr, knb, kro, vvb, ksb, vsb, kwb,
                                           vwb, gatef, attn);

    // output projection
    gemm(attn, w_proj, out, BT, CDIM, 512);
}

// Round 2
// 2448.771 us; speedup vs baseline: 1.5907x; 1.5907x over previous
//
#include <hip/hip_runtime.h>
#include <math.h>

#define T_SEQ   1024
#define BATCH   2
#define CDIM    1024
#define NHEAD   16
#define VHEAD   32
#define NOPE_D  32
#define ROPED   64
#define KEEP    256
#define HEAD_D  96   // NOPE + ROPE
#define SCALE_ATTN 0.1020620726159658f  // 1/sqrt(96)

// flash tile params
#define BQ   32     // queries per block
#define BKT  64     // keys per tile
#define SK   100    // Q/K LDS row stride (floats): mult of 4, k*100%32=4k -> <=2-way on b128
#define SPT  34     // Pt row stride [k][q]: even -> aligned b64 column pairs
#define SPV  36     // V LDS row stride: mult of 4 for float4 staging, conflict-free b64 reads

// ---------------------------------------------------------------------------
// Generic fp32 tiled GEMM: C[M,N] = A[M,K] @ B[K,N], row-major.
// ---------------------------------------------------------------------------
__global__ __launch_bounds__(256) void gemm_tiled(const float* __restrict__ A,
                                                  const float* __restrict__ B,
                                                  float* __restrict__ C,
                                                  int M, int N, int K) {
    __shared__ float As[16][65];
    __shared__ float Bs[16][64];
    int tid = threadIdx.x;
    int tx = tid & 15, ty = tid >> 4;
    int row0 = blockIdx.y * 64, col0 = blockIdx.x * 64;
    float acc[4][4] = {};
    for (int k0 = 0; k0 < K; k0 += 16) {
#pragma unroll
        for (int r = 0; r < 4; r++) {
            int idx = tid + 256 * r;
            int kk = idx & 15, m = idx >> 4;
            int gr = row0 + m, gc = k0 + kk;
            As[kk][m] = (gr < M && gc < K) ? A[(size_t)gr * K + gc] : 0.f;
        }
#pragma unroll
        for (int r = 0; r < 4; r++) {
            int idx = tid + 256 * r;
            int n = idx & 63, kk = idx >> 6;
            int gr = k0 + kk, gc = col0 + n;
            Bs[kk][n] = (gr < K && gc < N) ? B[(size_t)gr * N + gc] : 0.f;
        }
        __syncthreads();
#pragma unroll
        for (int kk = 0; kk < 16; kk++) {
            float a[4], b[4];
#pragma unroll
            for (int i = 0; i < 4; i++) a[i] = As[kk][ty + 16 * i];
#pragma unroll
            for (int j = 0; j < 4; j++) b[j] = Bs[kk][tx + 16 * j];
#pragma unroll
            for (int i = 0; i < 4; i++)
#pragma unroll
                for (int j = 0; j < 4; j++) acc[i][j] += a[i] * b[j];
        }
        __syncthreads();
    }
#pragma unroll
    for (int i = 0; i < 4; i++) {
        int gr = row0 + ty + 16 * i;
        if (gr >= M) continue;
#pragma unroll
        for (int j = 0; j < 4; j++) {
            int gc = col0 + tx + 16 * j;
            if (gc < N) C[(size_t)gr * N + gc] = acc[i][j];
        }
    }
}

// ---------------------------------------------------------------------------
__global__ void rms_rows(float* __restrict__ buf, const float* __restrict__ g, int D) {
    int row = blockIdx.x;
    int lane = threadIdx.x;  // blockDim = 64
    float ss = 0.f;
    for (int d = lane; d < D; d += 64) {
        float v = buf[(size_t)row * D + d];
        ss += v * v;
    }
    for (int off = 32; off; off >>= 1) ss += __shfl_xor(ss, off, 64);
    float r = rsqrtf(ss / (float)D + 1e-6f);
    for (int d = lane; d < D; d += 64) buf[(size_t)row * D + d] *= r * g[d];
}

// ---------------------------------------------------------------------------
__global__ void rope_inplace(float* __restrict__ buf, int nrows, int rstride,
                             int nheads, int hstride, int roff, int posmod,
                             float scale) {
    int total = nrows * nheads * 32;
    for (int it = blockIdx.x * blockDim.x + threadIdx.x; it < total;
         it += gridDim.x * blockDim.x) {
        int i = it & 31;
        int hr = it >> 5;
        int h = hr % nheads;
        int row = hr / nheads;
        int pos = row % posmod;
        float expo = (float)i * (1.0f / 32.0f);
        float f = 1.0f / powf(10000.0f, expo);
        float a = (float)pos * f;
        float s, c;
        sincosf(a, &s, &c);
        size_t base = (size_t)row * rstride + (size_t)h * hstride + roff;
        float v1 = buf[base + i], v2 = buf[base + 32 + i];
        buf[base + i]      = (v1 * c - v2 * s) * scale;
        buf[base + 32 + i] = (v1 * s + v2 * c) * scale;
    }
}

// ---------------------------------------------------------------------------
__global__ void scores_gate(const float* __restrict__ x,
                            const float* __restrict__ w_imp,
                            const float* __restrict__ w_gate,
                            float* __restrict__ scores,
                            float* __restrict__ gate_raw) {
    int wid = (blockIdx.x * blockDim.x + threadIdx.x) >> 6;
    int lane = threadIdx.x & 63;
    if (wid >= BATCH * T_SEQ) return;
    int b = wid >> 10;
    const float* xr = x + (size_t)wid * CDIM;
    float s0 = 0, g0 = 0, g1 = 0, g2 = 0;
    for (int c = lane; c < CDIM; c += 64) {
        float xv = xr[c];
        s0 += xv * w_imp[c];
        g0 += xv * w_gate[c * 3 + 0];
        g1 += xv * w_gate[c * 3 + 1];
        g2 += xv * w_gate[c * 3 + 2];
    }
    for (int off = 32; off; off >>= 1) {
        s0 += __shfl_xor(s0, off, 64);
        g0 += __shfl_xor(g0, off, 64);
        g1 += __shfl_xor(g1, off, 64);
        g2 += __shfl_xor(g2, off, 64);
    }
    if (lane == 0) {
        scores[wid] = s0;
        atomicAdd(&gate_raw[b * 3 + 0], g0);
        atomicAdd(&gate_raw[b * 3 + 1], g1);
        atomicAdd(&gate_raw[b * 3 + 2], g2);
    }
}

__global__ void gate_final(const float* __restrict__ gate_raw, float* __restrict__ gate) {
    int b = threadIdx.x;
    if (b >= BATCH) return;
    float v0 = gate_raw[b * 3 + 0] / (float)T_SEQ;
    float v1 = gate_raw[b * 3 + 1] / (float)T_SEQ;
    float v2 = gate_raw[b * 3 + 2] / (float)T_SEQ;
    float m = fmaxf(v0, fmaxf(v1, v2));
    float e0 = expf(v0 - m), e1 = expf(v1 - m), e2 = expf(v2 - m);
    float s = e0 + e1 + e2;
    gate[b * 3 + 0] = e0 / s;
    gate[b * 3 + 1] = e1 / s;
    gate[b * 3 + 2] = e2 / s;
}

// ---------------------------------------------------------------------------
__global__ void topk_kernel(const float* __restrict__ scores, int* __restrict__ idx) {
    int b = blockIdx.x;
    __shared__ float s[1024];
    __shared__ int ps[1024];
    int t = threadIdx.x;
    s[t] = scores[b * T_SEQ + t];
    __syncthreads();
    float mine = s[t];
    int rank = 0;
    for (int j = 0; j < 1024; j++) {
        float v = s[j];
        rank += (v > mine) || (v == mine && j < t);
    }
    int selv = (rank < KEEP) ? 1 : 0;
    ps[t] = selv;
    __syncthreads();
    for (int off = 1; off < 1024; off <<= 1) {
        int add = (t >= off) ? ps[t - off] : 0;
        __syncthreads();
        ps[t] += add;
        __syncthreads();
    }
    if (selv) idx[b * KEEP + ps[t] - 1] = t;
}

__global__ void gather_sel(const float* __restrict__ x, const int* __restrict__ idx,
                           float* __restrict__ sel) {
    for (size_t i = (size_t)blockIdx.x * blockDim.x + threadIdx.x;
         i < (size_t)BATCH * KEEP * CDIM; i += (size_t)gridDim.x * blockDim.x) {
        int c = (int)(i & (CDIM - 1));
        int r = (int)((i >> 10) & (KEEP - 1));
        int b = (int)(i >> 18);
        sel[i] = x[((size_t)b * T_SEQ + idx[b * KEEP + r]) * CDIM + c];
    }
}

// ---------------------------------------------------------------------------
// Fused 3-branch flash attention v2: 32-query x 64-key tiles, register
// micro-tiled S and PV, block-wide online softmax through LDS Pt[k][q].
// Grid: (T/32, NHEAD, BATCH), 256 threads.
// ---------------------------------------------------------------------------
__global__ __launch_bounds__(256) void flash_fused(
    const float* __restrict__ qn, const float* __restrict__ qr,
    const float* __restrict__ kn, const float* __restrict__ kr,
    const float* __restrict__ v1, const float* __restrict__ ksr,
    const float* __restrict__ vsr, const float* __restrict__ kwr,
    const float* __restrict__ vwr, const float* __restrict__ gate,
    float* __restrict__ out) {
    __shared__ float Qs[BQ * SK];    // 32 x 96 (stride 100)
    __shared__ float Ks[BKT * SK];   // 64 x 96 (stride 100)
    __shared__ float Vs[BKT * SPV];  // 64 x 32 (stride 36)
    __shared__ float Pt[BKT * SPT];  // [k][q] (stride 34)
    __shared__ float mrow[BQ], lrow[BQ], arow[BQ], mtil[BQ];

    int b = blockIdx.z, h = blockIdx.y;
    int q0 = blockIdx.x * BQ;
    int t = threadIdx.x;
    int tq = t >> 4, tk = t & 15;   // S mapping: q=2*tq+i, k=16*j+tk
    int qg = t >> 4, dg = t & 15;   // PV mapping: q=2*qg+i, d=2*dg+j

    // stage Q tile (32 rows x 24 float4)
    for (int i = t; i < BQ * 24; i += 256) {
        int row = i / 24, d4 = i % 24;
        size_t rq = (size_t)b * T_SEQ + q0 + row;
        float4 v;
        if (d4 < 8) v = *(const float4*)&qn[rq * 512 + h * 32 + d4 * 4];
        else        v = *(const float4*)&qr[rq * 1024 + h * 64 + (d4 - 8) * 4];
        *(float4*)&Qs[row * SK + d4 * 4] = v;
    }

    float comb[2][2] = {};
    for (int phase = 0; phase < 3; phase++) {
        bool causal = (phase != 1);
        int ntiles = causal ? ((q0 + BQ - 1) / BKT + 1) : (KEEP / BKT);
        float o00 = 0.f, o01 = 0.f, o10 = 0.f, o11 = 0.f;
        __syncthreads();   // previous phase readers of lrow done
        if (t < BQ) { mrow[t] = -1e30f; lrow[t] = 0.f; }

        for (int kt = 0; kt < ntiles; kt++) {
            int j0 = kt * BKT;
            __syncthreads();  // previous tile readers of Ks/Vs/Pt done (also covers Qs/mrow first time)

            // stage K tile (64 rows x 24 float4)
            for (int i = t; i < BKT * 24; i += 256) {
                int row = i / 24, d4 = i % 24;
                int j = j0 + row;
                float4 v;
                if (phase == 0) {
                    size_t rk = (size_t)b * T_SEQ + j;
                    if (d4 < 8) v = *(const float4*)&kn[rk * 512 + h * 32 + d4 * 4];
                    else        v = *(const float4*)&kr[rk * 64 + (d4 - 8) * 4];
                } else if (phase == 1) {
                    v = *(const float4*)&ksr[((size_t)b * KEEP + j) * 1536 + h * 96 + d4 * 4];
                } else {
                    v = *(const float4*)&kwr[((size_t)b * T_SEQ + j) * 1536 + h * 96 + d4 * 4];
                }
                *(float4*)&Ks[row * SK + d4 * 4] = v;
            }
            // stage V tile (64 rows x 8 float4)
            for (int i = t; i < BKT * 8; i += 256) {
                int row = i >> 3, d4 = i & 7;
                int j = j0 + row;
                float4 v;
                if (phase == 0)      v = *(const float4*)&v1 [((size_t)b * T_SEQ + j) * 512 + h * 32 + d4 * 4];
                else if (phase == 1) v = *(const float4*)&vsr[((size_t)b * KEEP  + j) * 512 + h * 32 + d4 * 4];
                else                 v = *(const float4*)&vwr[((size_t)b * T_SEQ + j) * 512 + h * 32 + d4 * 4];
                *(float4*)&Vs[row * SPV + d4 * 4] = v;
            }
            __syncthreads();

            // S = Q.K^T  (2q x 4k per thread)
            float s[2][4] = {};
#pragma unroll 6
            for (int d = 0; d < HEAD_D; d += 4) {
                float4 qa = *(float4*)&Qs[(2 * tq)     * SK + d];
                float4 qb = *(float4*)&Qs[(2 * tq + 1) * SK + d];
#pragma unroll
                for (int j = 0; j < 4; j++) {
                    float4 kv = *(float4*)&Ks[(16 * j + tk) * SK + d];
                    s[0][j] += qa.x * kv.x + qa.y * kv.y + qa.z * kv.z + qa.w * kv.w;
                    s[1][j] += qb.x * kv.x + qb.y * kv.y + qb.z * kv.z + qb.w * kv.w;
                }
            }
#pragma unroll
            for (int i = 0; i < 2; i++)
#pragma unroll
                for (int j = 0; j < 4; j++) {
                    int qq = q0 + 2 * tq + i;
                    int kk = j0 + 16 * j + tk;
                    float sv = s[i][j] * SCALE_ATTN;
                    if (causal && kk > qq) sv = -1e30f;
                    Pt[(16 * j + tk) * SPT + (2 * tq + i)] = sv;
                }
            __syncthreads();

            // tile row-max: q = t>>3, 8 lanes per row
            {
                int q = t >> 3, sub = t & 7;
                float mt = -1e30f;
#pragma unroll
                for (int i2 = 0; i2 < 8; i2++)
                    mt = fmaxf(mt, Pt[(sub * 8 + i2) * SPT + q]);
                mt = fmaxf(mt, __shfl_xor(mt, 1, 64));
                mt = fmaxf(mt, __shfl_xor(mt, 2, 64));
                mt = fmaxf(mt, __shfl_xor(mt, 4, 64));
                if (sub == 0) mtil[q] = mt;
            }
            __syncthreads();
            if (t < BQ) {
                float mnew = fmaxf(mrow[t], mtil[t]);
                arow[t] = __expf(mrow[t] - mnew);
                mrow[t] = mnew;
            }
            __syncthreads();
            // exponentiate + row sums
            {
                int q = t >> 3, sub = t & 7;
                float mnew = mrow[q];
                float psum = 0.f;
#pragma unroll
                for (int i2 = 0; i2 < 8; i2++) {
                    int kk = sub * 8 + i2;
                    float p = __expf(Pt[kk * SPT + q] - mnew);
                    Pt[kk * SPT + q] = p;
                    psum += p;
                }
                psum += __shfl_xor(psum, 1, 64);
                psum += __shfl_xor(psum, 2, 64);
                psum += __shfl_xor(psum, 4, 64);
                if (sub == 0) lrow[q] = lrow[q] * arow[q] + psum;
            }
            __syncthreads();

            // O accumulate (2q x 2d per thread)
            {
                float a0 = arow[2 * qg], a1 = arow[2 * qg + 1];
                o00 *= a0; o01 *= a0; o10 *= a1; o11 *= a1;
#pragma unroll 8
                for (int kk = 0; kk < BKT; kk++) {
                    float2 pv = *(float2*)&Pt[kk * SPT + 2 * qg];
                    float2 vv = *(float2*)&Vs[kk * SPV + 2 * dg];
                    o00 += pv.x * vv.x; o01 += pv.x * vv.y;
                    o10 += pv.y * vv.x; o11 += pv.y * vv.y;
                }
            }
        }  // key tiles

        // gate combine (lrow visible: synced after exp step of last tile)
        {
            float g = gate[b * 3 + phase];
            float i0 = g / lrow[2 * qg], i1 = g / lrow[2 * qg + 1];
            comb[0][0] += o00 * i0; comb[0][1] += o01 * i0;
            comb[1][0] += o10 * i1; comb[1][1] += o11 * i1;
        }
    }  // phases

    size_t r0 = ((size_t)b * T_SEQ + q0 + 2 * qg) * 512 + h * 32 + 2 * dg;
    out[r0]           = comb[0][0];
    out[r0 + 1]       = comb[0][1];
    out[r0 + 512]     = comb[1][0];
    out[r0 + 512 + 1] = comb[1][1];
}

// ---------------------------------------------------------------------------
extern "C" void kernel_launch(void* const* d_in, const int* in_sizes, int n_in,
                              void* d_out, int out_size, void* d_ws, size_t ws_size,
                              hipStream_t stream) {
    const float* x        = (const float*)d_in[0];
    const float* w_cq     = (const float*)d_in[1];
    const float* g_qnorm  = (const float*)d_in[2];
    const float* w_dqn    = (const float*)d_in[3];
    const float* w_dqr    = (const float*)d_in[4];
    const float* w_ckv    = (const float*)d_in[5];
    const float* g_kvnorm = (const float*)d_in[6];
    const float* w_dkn    = (const float*)d_in[7];
    const float* w_dv     = (const float*)d_in[8];
    const float* w_krope  = (const float*)d_in[9];
    const float* w_imp    = (const float*)d_in[10];
    const float* w_selk   = (const float*)d_in[11];
    const float* w_selv   = (const float*)d_in[12];
    const float* w_wink   = (const float*)d_in[13];
    const float* w_winv   = (const float*)d_in[14];
    const float* w_gate   = (const float*)d_in[15];
    const float* w_proj   = (const float*)d_in[16];
    float* out = (float*)d_out;

    const int BT = BATCH * T_SEQ;  // 2048
    const int BS = BATCH * KEEP;   // 512

    float* ws = (float*)d_ws;
    size_t o = 0;
    float* nq     = ws + o; o += (size_t)BT * 96;
    float* ckv    = ws + o; o += (size_t)BT * 32;
    float* qn     = ws + o; o += (size_t)BT * 512;
    float* qr     = ws + o; o += (size_t)BT * 1024;
    float* knb    = ws + o; o += (size_t)BT * 512;
    float* vvb    = ws + o; o += (size_t)BT * 512;
    float* kro    = ws + o; o += (size_t)BT * 64;
    float* kwb    = ws + o; o += (size_t)BT * 1536;
    float* vwb    = ws + o; o += (size_t)BT * 512;
    float* ksb    = ws + o; o += (size_t)BS * 1536;
    float* vsb    = ws + o; o += (size_t)BS * 512;
    float* selb   = ws + o; o += (size_t)BS * CDIM;
    float* scores = ws + o; o += 2048;
    float* gateraw= ws + o; o += 8;
    float* gatef  = ws + o; o += 8;
    int*   idx    = (int*)(ws + o); o += 512;
    float* attn   = ws + o; o += (size_t)BT * 512;

    hipMemsetAsync(gateraw, 0, 8 * sizeof(float), stream);

    dim3 blk(256);
    auto gemm = [&](const float* A, const float* Bm, float* C, int M, int N, int K) {
        dim3 grid((N + 63) / 64, (M + 63) / 64);
        gemm_tiled<<<grid, blk, 0, stream>>>(A, Bm, C, M, N, K);
    };

    // Projections off x
    gemm(x, w_cq, nq, BT, 96, CDIM);
    rms_rows<<<BT, 64, 0, stream>>>(nq, g_qnorm, 96);
    gemm(nq, w_dqn, qn, BT, 512, 96);
    gemm(nq, w_dqr, qr, BT, 1024, 96);
    rope_inplace<<<2048, 256, 0, stream>>>(qr, BT, 1024, 16, 64, 0, T_SEQ, 1.0f);

    gemm(x, w_ckv, ckv, BT, 32, CDIM);
    rms_rows<<<BT, 64, 0, stream>>>(ckv, g_kvnorm, 32);
    gemm(ckv, w_dkn, knb, BT, 512, 32);
    gemm(ckv, w_dv, vvb, BT, 512, 32);

    gemm(x, w_krope, kro, BT, 64, CDIM);
    rope_inplace<<<256, 256, 0, stream>>>(kro, BT, 64, 1, 0, 0, T_SEQ, 1.0f / NHEAD);

    gemm(x, w_wink, kwb, BT, 1536, CDIM);
    rope_inplace<<<2048, 256, 0, stream>>>(kwb, BT, 1536, 16, 96, 32, T_SEQ, 1.0f);
    gemm(x, w_winv, vwb, BT, 512, CDIM);

    // scores + gate
    scores_gate<<<(BT * 64 + 255) / 256, 256, 0, stream>>>(x, w_imp, w_gate, scores, gateraw);
    gate_final<<<1, 64, 0, stream>>>(gateraw, gatef);

    // top-k select
    topk_kernel<<<BATCH, 1024, 0, stream>>>(scores, idx);
    gather_sel<<<2048, 256, 0, stream>>>(x, idx, selb);
    gemm(selb, w_selk, ksb, BS, 1536, CDIM);
    rope_inplace<<<512, 256, 0, stream>>>(ksb, BS, 1536, 16, 96, 32, KEEP, 1.0f);
    gemm(selb, w_selv, vsb, BS, 512, CDIM);

    // fused attention
    dim3 fgrid(T_SEQ / BQ, NHEAD, BATCH);
    flash_fused<<<fgrid, 256, 0, stream>>>(qn, qr, knb, kro, vvb, ksb, vsb, kwb,
                                           vwb, gatef, attn);

    // output projection
    gemm(attn, w_proj, out, BT, CDIM, 512);
}